// Round 13
// baseline (503.430 us; speedup 1.0000x reference)
//
#include <hip/hip_runtime.h>

// FlatST: GAT autoencoder + smoothing. Bucketed counting-sort CSR build,
// gload_lds-pipelined big GEMMs, direct-MFMA small GEMMs, shuffle-free
// wide-vector CSR gathers (adj/ps/qn broadcast via L1, per-lane scores),
// bf16 tables. N=100000, E=800000, IN=256, HID=128, OUT=32.

#define SELU_S 1.0507009873554805f
#define SELU_A 1.6732632423543772f

typedef short bf16x8 __attribute__((ext_vector_type(8)));
typedef float f32x4 __attribute__((ext_vector_type(4)));

__device__ __forceinline__ float selu_f(float v){
  return v > 0.f ? SELU_S * v : SELU_S * SELU_A * (__expf(v) - 1.f);
}
__device__ __forceinline__ float b2f(unsigned short u){
  return __uint_as_float((unsigned)u << 16);
}
__device__ __forceinline__ unsigned short f2b(float f){
  unsigned u = __float_as_uint(f);
  u += 0x7fffu + ((u >> 16) & 1u);   // RNE
  return (unsigned short)(u >> 16);
}
__device__ __forceinline__ unsigned packbf(float a, float b){
  return (unsigned)f2b(a) | ((unsigned)f2b(b) << 16);
}
__device__ __forceinline__ void unpack_acc(float* acc, unsigned u, float w){
  acc[0] += w * __uint_as_float(u << 16);
  acc[1] += w * __uint_as_float(u & 0xffff0000u);
}
template<int R> struct VecT;
template<> struct VecT<2>{ using type = unsigned int; };
template<> struct VecT<4>{ using type = uint2; };
template<> struct VecT<8>{ using type = uint4; };

// async global->LDS 16B
__device__ __forceinline__ void gload_lds16(const void* g, void* l){
  __builtin_amdgcn_global_load_lds(
      (const __attribute__((address_space(1))) unsigned int*)g,
      (__attribute__((address_space(3))) unsigned int*)l, 16, 0, 0);
}

// ---------- weight prep ----------
__global__ __launch_bounds__(256) void prep_weights(
    const float* __restrict__ W1s, const float* __restrict__ W2s,
    unsigned short* __restrict__ W1sT_h, unsigned short* __restrict__ W1s_h,
    unsigned short* __restrict__ W2sT_h, unsigned short* __restrict__ W2s_h){
  int t = blockIdx.x * 256 + threadIdx.x;
  if (t < 32768){
    W1s_h[t] = f2b(W1s[t]);                  // [256][128]
    int k = t / 256, d = t % 256;            // W1sT_h [128][256]
    W1sT_h[t] = f2b(W1s[d * 128 + k]);
  }
  if (t < 4096){
    W2s_h[t] = f2b(W2s[t]);                  // [128][32]
    int k = t / 128, d = t % 128;            // W2sT_h [32][128]
    W2sT_h[t] = f2b(W2s[d * 32 + k]);
  }
}

// ---------- fused: X f32 -> Xh bf16 AND layer-1 dots ----------
__global__ __launch_bounds__(256) void cvt_dots(
    const float* __restrict__ X, unsigned short* __restrict__ Xh,
    const float* __restrict__ u1, const float* __restrict__ v1,
    float* __restrict__ p, float* __restrict__ q, int N){
  int g = blockIdx.x * 256 + threadIdx.x;
  int node = g >> 6, lane = g & 63;
  if (node >= N) return;
  float4 x = *reinterpret_cast<const float4*>(X + (size_t)node * 256 + lane * 4);
  uint2 r;
  r.x = packbf(x.x, x.y);
  r.y = packbf(x.z, x.w);
  *reinterpret_cast<uint2*>(Xh + (size_t)node * 256 + lane * 4) = r;
  float4 uu = *reinterpret_cast<const float4*>(u1 + lane * 4);
  float4 vv = *reinterpret_cast<const float4*>(v1 + lane * 4);
  float s1 = x.x*uu.x + x.y*uu.y + x.z*uu.z + x.w*uu.w;
  float s2 = x.x*vv.x + x.y*vv.y + x.z*vv.z + x.w*vv.w;
  for (int m = 32; m; m >>= 1){ s1 += __shfl_xor(s1, m); s2 += __shfl_xor(s2, m); }
  if (lane == 0){ p[node] = s1; q[node] = s2; }
}

// ---------- small precompute ----------
__global__ void precompute_vecs(const float* __restrict__ W1s, const float* __restrict__ W1d,
                                const float* __restrict__ a1s, const float* __restrict__ a1d,
                                const float* __restrict__ W2s, const float* __restrict__ W2d,
                                const float* __restrict__ a2s, const float* __restrict__ a2d,
                                const float* __restrict__ a3s, const float* __restrict__ a3d,
                                float* u1, float* v1, float* u2, float* v2,
                                float* u3, float* v3,
                                const float* alpha1, const float* alpha2, float* sscale){
  int t = threadIdx.x;
  float s1 = 0.f, s2 = 0.f;
  for (int j = 0; j < 128; j++){ s1 += W1s[t*128+j]*a1s[j]; s2 += W1d[t*128+j]*a1d[j]; }
  u1[t] = s1; v1[t] = s2;
  if (t < 128){
    float s3 = 0.f, s4 = 0.f;
    for (int j = 0; j < 32; j++){ s3 += W2s[t*32+j]*a2s[j]; s4 += W2d[t*32+j]*a2d[j]; }
    u2[t] = s3; v2[t] = s4;
  }
  if (t < 32){
    float s5 = 0.f, s6 = 0.f;
    for (int j = 0; j < 128; j++){ s5 += W2s[j*32+t]*a3s[j]; s6 += W2d[j*32+t]*a3d[j]; }
    u3[t] = s5; v3[t] = s6;
  }
  if (t == 0){
    float a = alpha1[0], b = alpha2[0];
    sscale[0] = 0.5f * (a*a + 4.f*b*b);
  }
}

// ================= bucketed CSR build =================
__global__ __launch_bounds__(256) void bucket_hist(
    const int* __restrict__ src, const int* __restrict__ dst,
    int* __restrict__ bcntD, int* __restrict__ bcntS, int E){
  __shared__ int hD[256], hS[256];
  int tid = threadIdx.x;
  hD[tid] = 0; hS[tid] = 0;
  __syncthreads();
  int base = blockIdx.x * 4096;
  for (int i = 0; i < 16; i++){
    int e = base + tid + i * 256;
    if (e < E){
      atomicAdd(&hD[dst[e] >> 9], 1);
      atomicAdd(&hS[src[e] >> 9], 1);
    }
  }
  __syncthreads();
  if (hD[tid]) atomicAdd(&bcntD[tid], hD[tid]);
  if (hS[tid]) atomicAdd(&bcntS[tid], hS[tid]);
}

__global__ void bucket_scan(const int* __restrict__ bcntD, const int* __restrict__ bcntS,
                            int* bbaseD, int* bbaseS, int* bcurD, int* bcurS, int NBK){
  __shared__ int t1[256], t2[256];
  int tid = threadIdx.x;
  int v1 = (tid < NBK) ? bcntD[tid] : 0;
  int v2 = (tid < NBK) ? bcntS[tid] : 0;
  t1[tid] = v1; t2[tid] = v2;
  __syncthreads();
  for (int off = 1; off < 256; off <<= 1){
    int a1 = (tid >= off) ? t1[tid - off] : 0;
    int a2 = (tid >= off) ? t2[tid - off] : 0;
    __syncthreads();
    t1[tid] += a1; t2[tid] += a2;
    __syncthreads();
  }
  int e1 = t1[tid] - v1, e2 = t2[tid] - v2;
  bbaseD[tid] = e1; bcurD[tid] = e1;
  bbaseS[tid] = e2; bcurS[tid] = e2;
  if (tid == NBK - 1){ bbaseD[NBK] = t1[tid]; bbaseS[NBK] = t2[tid]; }
}

__global__ __launch_bounds__(256) void bin_stage(
    const int* __restrict__ src, const int* __restrict__ dst,
    int* __restrict__ bcurD, int* __restrict__ bcurS,
    unsigned* __restrict__ stgD, unsigned* __restrict__ stgS, int E){
  __shared__ int hD[256], hS[256], bD[256], bS[256];
  int tid = threadIdx.x;
  hD[tid] = 0; hS[tid] = 0;
  __syncthreads();
  int base = blockIdx.x * 4096;
  int s[16], d[16];
  for (int i = 0; i < 16; i++){
    int e = base + tid + i * 256;
    if (e < E){
      s[i] = src[e]; d[i] = dst[e];
      atomicAdd(&hD[d[i] >> 9], 1);
      atomicAdd(&hS[s[i] >> 9], 1);
    } else s[i] = -1;
  }
  __syncthreads();
  bD[tid] = hD[tid] ? atomicAdd(&bcurD[tid], hD[tid]) : 0;
  bS[tid] = hS[tid] ? atomicAdd(&bcurS[tid], hS[tid]) : 0;
  hD[tid] = 0; hS[tid] = 0;
  __syncthreads();
  for (int i = 0; i < 16; i++){
    if (s[i] < 0) continue;
    int kb = d[i] >> 9;
    int pos = bD[kb] + atomicAdd(&hD[kb], 1);
    stgD[pos] = ((unsigned)(d[i] & 511) << 17) | (unsigned)s[i];
    kb = s[i] >> 9;
    pos = bS[kb] + atomicAdd(&hS[kb], 1);
    stgS[pos] = ((unsigned)(s[i] & 511) << 17) | (unsigned)d[i];
  }
}

__global__ __launch_bounds__(256) void place_csr(
    const unsigned* __restrict__ stgD, const unsigned* __restrict__ stgS,
    const int* __restrict__ bbaseD, const int* __restrict__ bbaseS,
    int* __restrict__ adjD, int* __restrict__ adjS,
    int* __restrict__ degD, int* __restrict__ offD,
    int* __restrict__ degS, int* __restrict__ offS,
    float* __restrict__ dis, float* __restrict__ pna, float* __restrict__ qn,
    int N, int NBK){
  bool isS = blockIdx.x >= (unsigned)NBK;
  int b = isS ? blockIdx.x - NBK : blockIdx.x;
  const unsigned* stg = isS ? stgS : stgD;
  const int* bbase = isS ? bbaseS : bbaseD;
  int* adj = isS ? adjS : adjD;
  int* deg = isS ? degS : degD;
  int* off = isS ? offS : offD;
  int n0 = b << 9;
  int r0 = bbase[b], r1 = bbase[b + 1];

  __shared__ int cnt[512];
  __shared__ int exc[512];
  __shared__ int tmp[256];
  int tid = threadIdx.x;
  cnt[2*tid] = 0; cnt[2*tid + 1] = 0;
  __syncthreads();
  for (int i = r0 + tid; i < r1; i += 256) atomicAdd(&cnt[stg[i] >> 17], 1);
  __syncthreads();
  int c0 = cnt[2*tid], c1 = cnt[2*tid + 1];
  int ts = c0 + c1;
  tmp[tid] = ts;
  __syncthreads();
  for (int o2 = 1; o2 < 256; o2 <<= 1){
    int a = (tid >= o2) ? tmp[tid - o2] : 0;
    __syncthreads();
    tmp[tid] += a;
    __syncthreads();
  }
  int e0 = tmp[tid] - ts;
  exc[2*tid] = e0; exc[2*tid + 1] = e0 + c0;
  __syncthreads();
  for (int l = tid; l < 512; l += 256){
    int n = n0 + l;
    if (n < N){
      deg[n] = cnt[l];
      off[n] = r0 + exc[l];
      if (isS){
        float dd = (float)cnt[l];
        float di = dd > 0.f ? powf(dd, -0.6f) : 0.f;
        float d2 = dd > 0.f ? powf(dd, -0.5f) : 0.f;
        float al = 1.f / (1.f + logf(dd + 1.f));
        dis[n] = di; pna[n] = d2 * al; qn[n] = d2;
      }
    }
  }
  __syncthreads();
  for (int l = tid; l < 512; l += 256) cnt[l] = r0 + exc[l];
  __syncthreads();
  for (int i = r0 + tid; i < r1; i += 256){
    unsigned p = stg[i];
    int pos = atomicAdd(&cnt[p >> 17], 1);
    adj[pos] = (int)(p & 0x1FFFFu);
  }
}

// ---------- fused GAT layer (shuffle-free gather) ----------
// G lanes per node, R = DIM/G elems/lane. Fast path (dg<=16): every lane loads
// all adj ids + scores (same addresses -> L1 broadcast), computes m/den locally.
template<int DIM, int G, bool ATTN, bool DO_SELU, bool OUT_BF16, bool DOTS>
__global__ __launch_bounds__(256) void fused_gat(
    const int* __restrict__ off, const int* __restrict__ degs, const int* __restrict__ adj,
    const float* __restrict__ ps, const float* __restrict__ pd,
    const unsigned short* __restrict__ xin, void* __restrict__ out_,
    const float* __restrict__ un, const float* __restrict__ vn,
    float* __restrict__ psn, float* __restrict__ pdn_o, int N){
  constexpr int R = DIM / G;
  using V = typename VecT<R>::type;
  int t = blockIdx.x * 256 + threadIdx.x;
  int node = t / G;
  int gl = t % G;
  if (node >= N) return;
  int base = (threadIdx.x & 63) & ~(G - 1);
  int o = off[node], dg = degs[node];
  float acc[R] = {};

  auto ldv = [&](int nj) -> V {
    return *reinterpret_cast<const V*>(xin + (size_t)nj * DIM + gl * R);
  };
  auto vacc = [&](V u, float wj){
    if constexpr (R == 2){
      unpack_acc(acc, u, wj);
    } else if constexpr (R == 4){
      unpack_acc(acc, u.x, wj); unpack_acc(acc + 2, u.y, wj);
    } else {
      unpack_acc(acc, u.x, wj); unpack_acc(acc + 2, u.y, wj);
      unpack_acc(acc + 4, u.z, wj); unpack_acc(acc + 6, u.w, wj);
    }
  };

  if (ATTN){
    float pdn = pd[node];
    if (dg <= 16){
      // shuffle-free: each lane holds all <=16 neighbor ids + weights
      int nid[16]; float w[16];
      #pragma unroll
      for (int j = 0; j < 16; j++) nid[j] = (j < dg) ? adj[o + j] : 0;
      float m = -1e30f;
      #pragma unroll
      for (int j = 0; j < 16; j++){
        if (j < dg){
          float s = ps[nid[j]] + pdn;
          s = s > 0.f ? s : 0.2f * s;
          w[j] = s;
          m = fmaxf(m, s);
        }
      }
      float den = 0.f;
      #pragma unroll
      for (int j = 0; j < 16; j++){
        if (j < dg){ w[j] = __expf(w[j] - m); den += w[j]; }
      }
      float inv = (dg > 0) ? 1.f / den : 0.f;
      #pragma unroll
      for (int j = 0; j < 16; j++){
        if (j < dg) vacc(ldv(nid[j]), w[j] * inv);
      }
    } else {
      // generic 3-pass fallback (rare), shuffle-based
      float m = -1e30f;
      for (int k = gl; k < dg; k += G){
        float s = ps[adj[o + k]] + pdn;
        s = s > 0.f ? s : 0.2f * s;
        m = fmaxf(m, s);
      }
      for (int msk = G >> 1; msk; msk >>= 1) m = fmaxf(m, __shfl_xor(m, msk));
      float den = 0.f;
      for (int k = gl; k < dg; k += G){
        float s = ps[adj[o + k]] + pdn;
        s = s > 0.f ? s : 0.2f * s;
        den += __expf(s - m);
      }
      for (int msk = G >> 1; msk; msk >>= 1) den += __shfl_xor(den, msk);
      float inv = 1.f / den;
      for (int c0 = 0; c0 < dg; c0 += 8){
        int cn = min(8, dg - c0);
        #pragma unroll
        for (int q = 0; q < 8; q++){
          if (q < cn){
            int nj = adj[o + c0 + q];
            float s = ps[nj] + pdn;
            s = s > 0.f ? s : 0.2f * s;
            vacc(ldv(nj), __expf(s - m) * inv);
          }
        }
      }
    }
  } else {
    for (int c0 = 0; c0 < dg; c0 += 16){
      int cn = min(16, dg - c0);
      #pragma unroll
      for (int q = 0; q < 16; q++){
        if (q < cn) vacc(ldv(adj[o + c0 + q]), 1.f);
      }
    }
    float inv = dg > 0 ? 1.f / (float)dg : 0.f;
    #pragma unroll
    for (int r = 0; r < R; r++) acc[r] *= inv;
  }
  if (DO_SELU){
    #pragma unroll
    for (int r = 0; r < R; r++) acc[r] = selu_f(acc[r]);
  }
  if (DOTS){
    float s1 = 0.f, s2 = 0.f;
    #pragma unroll
    for (int r = 0; r < R; r++){
      s1 += acc[r] * un[gl * R + r];
      s2 += acc[r] * vn[gl * R + r];
    }
    for (int msk = G >> 1; msk; msk >>= 1){ s1 += __shfl_xor(s1, msk); s2 += __shfl_xor(s2, msk); }
    if (gl == 0){ psn[node] = s1; pdn_o[node] = s2; }
  }
  if (OUT_BF16){
    unsigned short* out = (unsigned short*)out_;
    if constexpr (R == 2){
      *reinterpret_cast<unsigned*>(out + (size_t)node * DIM + gl * 2) = packbf(acc[0], acc[1]);
    } else if constexpr (R == 4){
      uint2 u; u.x = packbf(acc[0], acc[1]); u.y = packbf(acc[2], acc[3]);
      *reinterpret_cast<uint2*>(out + (size_t)node * DIM + gl * 4) = u;
    } else {
      uint4 u;
      u.x = packbf(acc[0], acc[1]); u.y = packbf(acc[2], acc[3]);
      u.z = packbf(acc[4], acc[5]); u.w = packbf(acc[6], acc[7]);
      *reinterpret_cast<uint4*>(out + (size_t)node * DIM + gl * 8) = u;
    }
  } else {
    float* out = (float*)out_;
    #pragma unroll
    for (int r = 0; r < R; r++) out[(size_t)node * DIM + gl * R + r] = acc[r];
  }
}

// ---------- fused smoothing step: G=8, uint2 per lane, shuffle-free ----------
template<bool OUT_B>
__global__ __launch_bounds__(256) void fused_smooth(
    const int* __restrict__ off, const int* __restrict__ degs, const int* __restrict__ adj,
    const float* __restrict__ pn, const float* __restrict__ qn,
    const float* __restrict__ scale,
    const unsigned short* __restrict__ xin, void* __restrict__ out_, int N){
  const int G = 8;
  int t = blockIdx.x * 256 + threadIdx.x;
  int node = t / G, gl = t % G;
  if (node >= N) return;
  int o = off[node], dg = degs[node];
  float pnv = pn[node] * (scale ? scale[0] : 1.f);
  float acc[4] = {};
  auto ldv = [&](int nj) -> uint2 {
    return *reinterpret_cast<const uint2*>(xin + (size_t)nj * 32 + gl * 4);
  };
  for (int c0 = 0; c0 < dg; c0 += 8){
    int cn = min(8, dg - c0);
    int nn[8]; float ww[8];
    #pragma unroll
    for (int q = 0; q < 8; q++){
      if (q < cn){ nn[q] = adj[o + c0 + q]; ww[q] = qn[nn[q]]; }
      else { nn[q] = 0; ww[q] = 0.f; }
    }
    #pragma unroll
    for (int q = 0; q < 8; q++){
      if (q < cn){
        uint2 u = ldv(nn[q]);
        unpack_acc(acc, u.x, ww[q]); unpack_acc(acc + 2, u.y, ww[q]);
      }
    }
  }
  #pragma unroll
  for (int r = 0; r < 4; r++) acc[r] *= pnv;
  if (OUT_B){
    uint2 u; u.x = packbf(acc[0], acc[1]); u.y = packbf(acc[2], acc[3]);
    *reinterpret_cast<uint2*>((unsigned short*)out_ + (size_t)node * 32 + gl * 4) = u;
  } else {
    float4 v; v.x = acc[0]; v.y = acc[1]; v.z = acc[2]; v.w = acc[3];
    *reinterpret_cast<float4*>((float*)out_ + (size_t)node * 32 + gl * 4) = v;
  }
}

// ---------- small bf16 MFMA GEMM (direct loads; for xs2/h3) ----------
template<int D, int K, int CB, bool DO_SELU, bool OUT_BF16>
__global__ __launch_bounds__(256) void gemm_mfma(
    const unsigned short* __restrict__ A, const unsigned short* __restrict__ Bt,
    void* __restrict__ Cout, int M){
  constexpr int NF = CB / 16;
  int wave = threadIdx.x >> 6;
  int lane = threadIdx.x & 63;
  int row0 = blockIdx.x * 64 + wave * 16;
  int col0 = blockIdx.y * CB;
  int l15 = lane & 15;
  int arow = row0 + l15;
  int g8 = (lane >> 4) * 8;
  bool rowok = arow < M;
  f32x4 acc[NF] = {};
  for (int k0 = 0; k0 < D; k0 += 32){
    bf16x8 a = {};
    if (rowok) a = *reinterpret_cast<const bf16x8*>(A + (size_t)arow * D + k0 + g8);
    #pragma unroll
    for (int f = 0; f < NF; f++){
      bf16x8 b = *reinterpret_cast<const bf16x8*>(
          Bt + (size_t)(col0 + f * 16 + l15) * D + k0 + g8);
      acc[f] = __builtin_amdgcn_mfma_f32_16x16x32_bf16(b, a, acc[f], 0, 0, 0);
    }
  }
  if (!rowok) return;
  int cb = (lane >> 4) * 4;
  #pragma unroll
  for (int f = 0; f < NF; f++){
    float v0 = acc[f][0], v1 = acc[f][1], v2 = acc[f][2], v3 = acc[f][3];
    if (DO_SELU){ v0 = selu_f(v0); v1 = selu_f(v1); v2 = selu_f(v2); v3 = selu_f(v3); }
    size_t idx = (size_t)arow * K + col0 + f * 16 + cb;
    if (OUT_BF16){
      uint2 u;
      u.x = packbf(v0, v1);
      u.y = packbf(v2, v3);
      *reinterpret_cast<uint2*>((unsigned short*)Cout + idx) = u;
    } else {
      f32x4 v = { v0, v1, v2, v3 };
      __builtin_nontemporal_store(v, reinterpret_cast<f32x4*>((float*)Cout + idx));
    }
  }
}

// ---------- pipelined bf16 MFMA GEMM (global_load_lds staged; for xs1/h4) ----------
template<int D, int K, bool DO_SELU, bool OUT_BF16>
__global__ __launch_bounds__(256) void gemm_pipe(
    const unsigned short* __restrict__ A, const unsigned short* __restrict__ Bt,
    void* __restrict__ Cout, int M){
  constexpr int NK = D / 32;
  constexpr int NF = K / 32;
  constexpr int AG = 2 * NK;
  constexpr int BG = 2 * NF * NK;
  extern __shared__ unsigned short smem[];
  unsigned short* Bs  = smem;
  unsigned short* As0 = smem + (size_t)K * D;
  unsigned short* As1 = As0 + 32 * D;

  const int w = threadIdx.x >> 6;
  const int lane = threadIdx.x & 63;
  const int rw = w & 1, cw = w >> 1;
  const int l15 = lane & 15, lhi = lane >> 4;

  for (int g = w; g < BG; g += 4){
    int k = g % NK, ff = g / NK;
    gload_lds16(Bt + (size_t)(ff * 16 + l15) * D + k * 32 + lhi * 8,
                Bs + (size_t)g * 512);
  }

  const int ntiles = M / 32;
  const int stride = gridDim.x;
  int t = blockIdx.x;

  auto stageA = [&](unsigned short* dstp, int tile){
    int row0 = tile * 32;
    for (int g = w; g < AG; g += 4){
      int k = g % NK, rr = g / NK;
      gload_lds16(A + (size_t)(row0 + rr * 16 + l15) * D + k * 32 + lhi * 8,
                  dstp + (size_t)g * 512);
    }
  };

  if (t < ntiles) stageA(As0, t);
  __syncthreads();

  int cur = 0;
  for (; t < ntiles; t += stride){
    unsigned short* curA = cur ? As1 : As0;
    unsigned short* nxtA = cur ? As0 : As1;
    int tn = t + stride;
    if (tn < ntiles) stageA(nxtA, tn);

    f32x4 acc[NF] = {};
    const unsigned short* Aw = curA + (size_t)rw * NK * 512;
    #pragma unroll
    for (int k = 0; k < NK; k++){
      bf16x8 a = *reinterpret_cast<const bf16x8*>(Aw + ((size_t)k * 64 + lane) * 8);
      #pragma unroll
      for (int f = 0; f < NF; f++){
        bf16x8 b = *reinterpret_cast<const bf16x8*>(
            Bs + (((size_t)(cw * NF + f) * NK + k) * 64 + lane) * 8);
        acc[f] = __builtin_amdgcn_mfma_f32_16x16x32_bf16(b, a, acc[f], 0, 0, 0);
      }
    }
    int row = t * 32 + rw * 16 + l15;
    #pragma unroll
    for (int f = 0; f < NF; f++){
      float v0 = acc[f][0], v1 = acc[f][1], v2 = acc[f][2], v3 = acc[f][3];
      if (DO_SELU){ v0 = selu_f(v0); v1 = selu_f(v1); v2 = selu_f(v2); v3 = selu_f(v3); }
      size_t idx = (size_t)row * K + cw * (K / 2) + f * 16 + lhi * 4;
      if (OUT_BF16){
        uint2 u;
        u.x = packbf(v0, v1);
        u.y = packbf(v2, v3);
        *reinterpret_cast<uint2*>((unsigned short*)Cout + idx) = u;
      } else {
        f32x4 v = { v0, v1, v2, v3 };
        __builtin_nontemporal_store(v, reinterpret_cast<f32x4*>((float*)Cout + idx));
      }
    }
    __syncthreads();
    cur ^= 1;
  }
}

extern "C" void kernel_launch(void* const* d_in, const int* in_sizes, int n_in,
                              void* d_out, int out_size, void* d_ws, size_t ws_size,
                              hipStream_t stream){
  const float* X    = (const float*)d_in[0];
  const int*   eidx = (const int*)d_in[1];
  const float* W1s  = (const float*)d_in[2];
  const float* W1d  = (const float*)d_in[3];
  const float* a1s  = (const float*)d_in[4];
  const float* a1d  = (const float*)d_in[5];
  const float* W2s  = (const float*)d_in[6];
  const float* W2d  = (const float*)d_in[7];
  const float* a2s  = (const float*)d_in[8];
  const float* a2d  = (const float*)d_in[9];
  const float* a3s  = (const float*)d_in[10];
  const float* a3d  = (const float*)d_in[11];
  const float* alpha1 = (const float*)d_in[14];
  const float* alpha2 = (const float*)d_in[15];

  const int N = in_sizes[0] / 256;
  const int E = in_sizes[1] / 2;
  const int* src = eidx;
  const int* dst = eidx + E;
  const int NBK = (N + 511) >> 9;

  float* out_sm = (float*)d_out;                    // [N,32]
  float* out_h4 = (float*)d_out + (size_t)N * 32;   // [N,256]

  float* ws = (float*)d_ws;
  size_t o = 0;
  unsigned short* Xh  = (unsigned short*)(ws + o); o += (size_t)N * 128; // [N,256] bf16
  unsigned short* B1h = (unsigned short*)(ws + o); o += (size_t)N * 64;  // xs1 / h3
  unsigned short* H1h = (unsigned short*)(ws + o); o += (size_t)N * 64;  // h1 / agg4
  unsigned short* B3h = (unsigned short*)(ws + o); o += (size_t)N * 16;  // xs2
  unsigned short* H2h = (unsigned short*)(ws + o); o += (size_t)N * 16;  // h2 (bf16)
  unsigned short* AGG3h = (unsigned short*)(ws + o); o += (size_t)N * 16; // agg3
  unsigned short* T1h = (unsigned short*)(ws + o); o += (size_t)N * 16;  // smooth tmp
  unsigned short* T2h = (unsigned short*)(ws + o); o += (size_t)N * 16;  // smooth tmp
  float* ps_a = ws + o; o += N;
  float* pd_a = ws + o; o += N;
  float* ps_b = ws + o; o += N;
  float* pd_b = ws + o; o += N;
  int* deg_in  = (int*)(ws + o); o += N;
  int* deg_src = (int*)(ws + o); o += N;
  int* off_dst = (int*)(ws + o); o += N;
  int* off_src = (int*)(ws + o); o += N;
  int* adj_dst = (int*)(ws + o); o += E;
  int* adj_src = (int*)(ws + o); o += E;
  unsigned* stgD = (unsigned*)(ws + o); o += E;
  unsigned* stgS = (unsigned*)(ws + o); o += E;
  int* bcntD  = (int*)(ws + o); o += 256;
  int* bcntS  = (int*)(ws + o); o += 256;
  int* bbaseD = (int*)(ws + o); o += 260;
  int* bbaseS = (int*)(ws + o); o += 260;
  int* bcurD  = (int*)(ws + o); o += 260;
  int* bcurS  = (int*)(ws + o); o += 260;
  float* dis = ws + o; o += N;
  float* pna = ws + o; o += N;
  float* qn  = ws + o; o += N;
  unsigned short* W1sT_h = (unsigned short*)(ws + o); o += 128 * 256 / 2;
  unsigned short* W2sT_h = (unsigned short*)(ws + o); o += 32 * 128 / 2;
  unsigned short* W2s_h  = (unsigned short*)(ws + o); o += 128 * 32 / 2;
  unsigned short* W1s_h  = (unsigned short*)(ws + o); o += 256 * 128 / 2;
  float* u1 = ws + o; o += 256;
  float* v1 = ws + o; o += 256;
  float* u2 = ws + o; o += 128;
  float* v2 = ws + o; o += 128;
  float* u3 = ws + o; o += 32;
  float* v3 = ws + o; o += 32;
  float* sscale = ws + o; o += 1;

  const int TPB = 256;
  const int EBLK = (E + 4095) / 4096;
  const int RB = (N + 63) / 64;
  auto blocksFor = [](size_t n){ return (unsigned)((n + 255) / 256); };

  // ---- small precompute first (u1/v1 needed by cvt_dots) ----
  precompute_vecs<<<1, 256, 0, stream>>>(W1s, W1d, a1s, a1d, W2s, W2d, a2s, a2d,
                                         a3s, a3d, u1, v1, u2, v2, u3, v3,
                                         alpha1, alpha2, sscale);
  prep_weights<<<128, 256, 0, stream>>>(W1s, W2s, W1sT_h, W1s_h, W2sT_h, W2s_h);
  cvt_dots<<<blocksFor((size_t)N * 64), TPB, 0, stream>>>(X, Xh, u1, v1, ps_a, pd_a, N);

  // ---- bucketed CSR build (both CSRs) ----
  (void)hipMemsetAsync(bcntD, 0, 512 * 4, stream);
  bucket_hist<<<EBLK, TPB, 0, stream>>>(src, dst, bcntD, bcntS, E);
  bucket_scan<<<1, 256, 0, stream>>>(bcntD, bcntS, bbaseD, bbaseS, bcurD, bcurS, NBK);
  bin_stage<<<EBLK, TPB, 0, stream>>>(src, dst, bcurD, bcurS, stgD, stgS, E);
  place_csr<<<2 * NBK, TPB, 0, stream>>>(stgD, stgS, bbaseD, bbaseS,
                                         adj_dst, adj_src, deg_in, off_dst,
                                         deg_src, off_src, dis, pna, qn, N, NBK);

  // ---- GAT layer 1: X(256) -> h1(128); epilogue dots for layer 2 ----
  {
    size_t lds = ((size_t)128 * 256 + 2 * 32 * 256) * 2;  // 96 KiB
    gemm_pipe<256, 128, false, true><<<256, TPB, lds, stream>>>(Xh, W1sT_h, B1h, N); // xs1
  }
  fused_gat<128, 16, true, true, true, true><<<blocksFor((size_t)N * 16), TPB, 0, stream>>>(
      off_dst, deg_in, adj_dst, ps_a, pd_a, B1h, H1h, u2, v2, ps_b, pd_b, N); // h1

  // ---- GAT layer 2: h1(128) -> h2(32); epilogue dots for layer 3 ----
  { dim3 g(RB, 1); gemm_mfma<128, 32, 32, false, true><<<g, TPB, 0, stream>>>(H1h, W2sT_h, B3h, N); } // xs2
  fused_gat<32, 16, true, false, true, true><<<blocksFor((size_t)N * 16), TPB, 0, stream>>>(
      off_dst, deg_in, adj_dst, ps_b, pd_b, B3h, H2h, u3, v3, ps_a, pd_a, N); // h2 (bf16)

  // ---- GAT layer 3: h2(32) -> h3(128) ----
  fused_gat<32, 16, true, false, true, false><<<blocksFor((size_t)N * 16), TPB, 0, stream>>>(
      off_dst, deg_in, adj_dst, ps_a, pd_a, H2h, AGG3h, nullptr, nullptr, nullptr, nullptr, N);
  { dim3 g(RB, 2); gemm_mfma<32, 128, 64, true, true><<<g, TPB, 0, stream>>>(AGG3h, W2s_h, B1h, N); } // h3

  // ---- GAT layer 4 (uniform): aggregate h3 then GEMM with W1s^T ----
  fused_gat<128, 16, false, false, true, false><<<blocksFor((size_t)N * 16), TPB, 0, stream>>>(
      off_dst, deg_in, adj_dst, nullptr, nullptr, B1h, H1h, nullptr, nullptr, nullptr, nullptr, N);
  {
    size_t lds = ((size_t)256 * 128 + 2 * 32 * 128) * 2;  // 80 KiB
    gemm_pipe<128, 256, false, false><<<512, TPB, lds, stream>>>(H1h, W1s_h, out_h4, N); // h4
  }

  // ---- smoothing: sm = Norm^2 * (0.5(a1^2+4a2^2) * C^2 h2), bf16 tables ----
  fused_smooth<true><<<blocksFor((size_t)N * 8), TPB, 0, stream>>>(
      off_src, deg_src, adj_src, dis, dis, nullptr, H2h, T1h, N);
  fused_smooth<true><<<blocksFor((size_t)N * 8), TPB, 0, stream>>>(
      off_src, deg_src, adj_src, dis, dis, sscale, T1h, T2h, N);
  fused_smooth<true><<<blocksFor((size_t)N * 8), TPB, 0, stream>>>(
      off_src, deg_src, adj_src, pna, qn, nullptr, T2h, T1h, N);
  fused_smooth<false><<<blocksFor((size_t)N * 8), TPB, 0, stream>>>(
      off_src, deg_src, adj_src, pna, qn, nullptr, T1h, out_sm, N);
}

// Round 14
// 405.853 us; speedup vs baseline: 1.2404x; 1.2404x over previous
//
#include <hip/hip_runtime.h>

// FlatST: GAT autoencoder + smoothing. Bucketed counting-sort CSR build,
// gload_lds-pipelined big GEMMs, direct-MFMA small GEMMs, wide-vector CSR
// gathers (16B/lane for 128-dim, 8B/lane smoothing), bf16 tables.
// N=100000, E=800000, IN=256, HID=128, OUT=32.  [Round-12 structure]

#define SELU_S 1.0507009873554805f
#define SELU_A 1.6732632423543772f

typedef short bf16x8 __attribute__((ext_vector_type(8)));
typedef float f32x4 __attribute__((ext_vector_type(4)));

__device__ __forceinline__ float selu_f(float v){
  return v > 0.f ? SELU_S * v : SELU_S * SELU_A * (__expf(v) - 1.f);
}
__device__ __forceinline__ float b2f(unsigned short u){
  return __uint_as_float((unsigned)u << 16);
}
__device__ __forceinline__ unsigned short f2b(float f){
  unsigned u = __float_as_uint(f);
  u += 0x7fffu + ((u >> 16) & 1u);   // RNE
  return (unsigned short)(u >> 16);
}
__device__ __forceinline__ unsigned packbf(float a, float b){
  return (unsigned)f2b(a) | ((unsigned)f2b(b) << 16);
}
__device__ __forceinline__ void unpack_acc(float* acc, unsigned u, float w){
  acc[0] += w * __uint_as_float(u << 16);
  acc[1] += w * __uint_as_float(u & 0xffff0000u);
}
template<int R> struct VecT;
template<> struct VecT<2>{ using type = unsigned int; };
template<> struct VecT<4>{ using type = uint2; };
template<> struct VecT<8>{ using type = uint4; };

// async global->LDS 16B
__device__ __forceinline__ void gload_lds16(const void* g, void* l){
  __builtin_amdgcn_global_load_lds(
      (const __attribute__((address_space(1))) unsigned int*)g,
      (__attribute__((address_space(3))) unsigned int*)l, 16, 0, 0);
}

// ---------- weight prep ----------
__global__ __launch_bounds__(256) void prep_weights(
    const float* __restrict__ W1s, const float* __restrict__ W2s,
    unsigned short* __restrict__ W1sT_h, unsigned short* __restrict__ W1s_h,
    unsigned short* __restrict__ W2sT_h, unsigned short* __restrict__ W2s_h){
  int t = blockIdx.x * 256 + threadIdx.x;
  if (t < 32768){
    W1s_h[t] = f2b(W1s[t]);                  // [256][128]
    int k = t / 256, d = t % 256;            // W1sT_h [128][256]
    W1sT_h[t] = f2b(W1s[d * 128 + k]);
  }
  if (t < 4096){
    W2s_h[t] = f2b(W2s[t]);                  // [128][32]
    int k = t / 128, d = t % 128;            // W2sT_h [32][128]
    W2sT_h[t] = f2b(W2s[d * 32 + k]);
  }
}

// ---------- fused: X f32 -> Xh bf16 AND layer-1 dots ----------
__global__ __launch_bounds__(256) void cvt_dots(
    const float* __restrict__ X, unsigned short* __restrict__ Xh,
    const float* __restrict__ u1, const float* __restrict__ v1,
    float* __restrict__ p, float* __restrict__ q, int N){
  int g = blockIdx.x * 256 + threadIdx.x;
  int node = g >> 6, lane = g & 63;
  if (node >= N) return;
  float4 x = *reinterpret_cast<const float4*>(X + (size_t)node * 256 + lane * 4);
  uint2 r;
  r.x = packbf(x.x, x.y);
  r.y = packbf(x.z, x.w);
  *reinterpret_cast<uint2*>(Xh + (size_t)node * 256 + lane * 4) = r;
  float4 uu = *reinterpret_cast<const float4*>(u1 + lane * 4);
  float4 vv = *reinterpret_cast<const float4*>(v1 + lane * 4);
  float s1 = x.x*uu.x + x.y*uu.y + x.z*uu.z + x.w*uu.w;
  float s2 = x.x*vv.x + x.y*vv.y + x.z*vv.z + x.w*vv.w;
  for (int m = 32; m; m >>= 1){ s1 += __shfl_xor(s1, m); s2 += __shfl_xor(s2, m); }
  if (lane == 0){ p[node] = s1; q[node] = s2; }
}

// ---------- small precompute ----------
__global__ void precompute_vecs(const float* __restrict__ W1s, const float* __restrict__ W1d,
                                const float* __restrict__ a1s, const float* __restrict__ a1d,
                                const float* __restrict__ W2s, const float* __restrict__ W2d,
                                const float* __restrict__ a2s, const float* __restrict__ a2d,
                                const float* __restrict__ a3s, const float* __restrict__ a3d,
                                float* u1, float* v1, float* u2, float* v2,
                                float* u3, float* v3,
                                const float* alpha1, const float* alpha2, float* sscale){
  int t = threadIdx.x;
  float s1 = 0.f, s2 = 0.f;
  for (int j = 0; j < 128; j++){ s1 += W1s[t*128+j]*a1s[j]; s2 += W1d[t*128+j]*a1d[j]; }
  u1[t] = s1; v1[t] = s2;
  if (t < 128){
    float s3 = 0.f, s4 = 0.f;
    for (int j = 0; j < 32; j++){ s3 += W2s[t*32+j]*a2s[j]; s4 += W2d[t*32+j]*a2d[j]; }
    u2[t] = s3; v2[t] = s4;
  }
  if (t < 32){
    float s5 = 0.f, s6 = 0.f;
    for (int j = 0; j < 128; j++){ s5 += W2s[j*32+t]*a3s[j]; s6 += W2d[j*32+t]*a3d[j]; }
    u3[t] = s5; v3[t] = s6;
  }
  if (t == 0){
    float a = alpha1[0], b = alpha2[0];
    sscale[0] = 0.5f * (a*a + 4.f*b*b);
  }
}

// ================= bucketed CSR build =================
__global__ __launch_bounds__(256) void bucket_hist(
    const int* __restrict__ src, const int* __restrict__ dst,
    int* __restrict__ bcntD, int* __restrict__ bcntS, int E){
  __shared__ int hD[256], hS[256];
  int tid = threadIdx.x;
  hD[tid] = 0; hS[tid] = 0;
  __syncthreads();
  int base = blockIdx.x * 4096;
  for (int i = 0; i < 16; i++){
    int e = base + tid + i * 256;
    if (e < E){
      atomicAdd(&hD[dst[e] >> 9], 1);
      atomicAdd(&hS[src[e] >> 9], 1);
    }
  }
  __syncthreads();
  if (hD[tid]) atomicAdd(&bcntD[tid], hD[tid]);
  if (hS[tid]) atomicAdd(&bcntS[tid], hS[tid]);
}

__global__ void bucket_scan(const int* __restrict__ bcntD, const int* __restrict__ bcntS,
                            int* bbaseD, int* bbaseS, int* bcurD, int* bcurS, int NBK){
  __shared__ int t1[256], t2[256];
  int tid = threadIdx.x;
  int v1 = (tid < NBK) ? bcntD[tid] : 0;
  int v2 = (tid < NBK) ? bcntS[tid] : 0;
  t1[tid] = v1; t2[tid] = v2;
  __syncthreads();
  for (int off = 1; off < 256; off <<= 1){
    int a1 = (tid >= off) ? t1[tid - off] : 0;
    int a2 = (tid >= off) ? t2[tid - off] : 0;
    __syncthreads();
    t1[tid] += a1; t2[tid] += a2;
    __syncthreads();
  }
  int e1 = t1[tid] - v1, e2 = t2[tid] - v2;
  bbaseD[tid] = e1; bcurD[tid] = e1;
  bbaseS[tid] = e2; bcurS[tid] = e2;
  if (tid == NBK - 1){ bbaseD[NBK] = t1[tid]; bbaseS[NBK] = t2[tid]; }
}

__global__ __launch_bounds__(256) void bin_stage(
    const int* __restrict__ src, const int* __restrict__ dst,
    int* __restrict__ bcurD, int* __restrict__ bcurS,
    unsigned* __restrict__ stgD, unsigned* __restrict__ stgS, int E){
  __shared__ int hD[256], hS[256], bD[256], bS[256];
  int tid = threadIdx.x;
  hD[tid] = 0; hS[tid] = 0;
  __syncthreads();
  int base = blockIdx.x * 4096;
  int s[16], d[16];
  for (int i = 0; i < 16; i++){
    int e = base + tid + i * 256;
    if (e < E){
      s[i] = src[e]; d[i] = dst[e];
      atomicAdd(&hD[d[i] >> 9], 1);
      atomicAdd(&hS[s[i] >> 9], 1);
    } else s[i] = -1;
  }
  __syncthreads();
  bD[tid] = hD[tid] ? atomicAdd(&bcurD[tid], hD[tid]) : 0;
  bS[tid] = hS[tid] ? atomicAdd(&bcurS[tid], hS[tid]) : 0;
  hD[tid] = 0; hS[tid] = 0;
  __syncthreads();
  for (int i = 0; i < 16; i++){
    if (s[i] < 0) continue;
    int kb = d[i] >> 9;
    int pos = bD[kb] + atomicAdd(&hD[kb], 1);
    stgD[pos] = ((unsigned)(d[i] & 511) << 17) | (unsigned)s[i];
    kb = s[i] >> 9;
    pos = bS[kb] + atomicAdd(&hS[kb], 1);
    stgS[pos] = ((unsigned)(s[i] & 511) << 17) | (unsigned)d[i];
  }
}

__global__ __launch_bounds__(256) void place_csr(
    const unsigned* __restrict__ stgD, const unsigned* __restrict__ stgS,
    const int* __restrict__ bbaseD, const int* __restrict__ bbaseS,
    int* __restrict__ adjD, int* __restrict__ adjS,
    int* __restrict__ degD, int* __restrict__ offD,
    int* __restrict__ degS, int* __restrict__ offS,
    float* __restrict__ dis, float* __restrict__ pna, float* __restrict__ qn,
    int N, int NBK){
  bool isS = blockIdx.x >= (unsigned)NBK;
  int b = isS ? blockIdx.x - NBK : blockIdx.x;
  const unsigned* stg = isS ? stgS : stgD;
  const int* bbase = isS ? bbaseS : bbaseD;
  int* adj = isS ? adjS : adjD;
  int* deg = isS ? degS : degD;
  int* off = isS ? offS : offD;
  int n0 = b << 9;
  int r0 = bbase[b], r1 = bbase[b + 1];

  __shared__ int cnt[512];
  __shared__ int exc[512];
  __shared__ int tmp[256];
  int tid = threadIdx.x;
  cnt[2*tid] = 0; cnt[2*tid + 1] = 0;
  __syncthreads();
  for (int i = r0 + tid; i < r1; i += 256) atomicAdd(&cnt[stg[i] >> 17], 1);
  __syncthreads();
  int c0 = cnt[2*tid], c1 = cnt[2*tid + 1];
  int ts = c0 + c1;
  tmp[tid] = ts;
  __syncthreads();
  for (int o2 = 1; o2 < 256; o2 <<= 1){
    int a = (tid >= o2) ? tmp[tid - o2] : 0;
    __syncthreads();
    tmp[tid] += a;
    __syncthreads();
  }
  int e0 = tmp[tid] - ts;
  exc[2*tid] = e0; exc[2*tid + 1] = e0 + c0;
  __syncthreads();
  for (int l = tid; l < 512; l += 256){
    int n = n0 + l;
    if (n < N){
      deg[n] = cnt[l];
      off[n] = r0 + exc[l];
      if (isS){
        float dd = (float)cnt[l];
        float di = dd > 0.f ? powf(dd, -0.6f) : 0.f;
        float d2 = dd > 0.f ? powf(dd, -0.5f) : 0.f;
        float al = 1.f / (1.f + logf(dd + 1.f));
        dis[n] = di; pna[n] = d2 * al; qn[n] = d2;
      }
    }
  }
  __syncthreads();
  for (int l = tid; l < 512; l += 256) cnt[l] = r0 + exc[l];
  __syncthreads();
  for (int i = r0 + tid; i < r1; i += 256){
    unsigned p = stg[i];
    int pos = atomicAdd(&cnt[p >> 17], 1);
    adj[pos] = (int)(p & 0x1FFFFu);
  }
}

// ---------- fused GAT layer (vector-width templated gather) ----------
// G lanes per node, R = DIM/G elems/lane (vector load of R bf16).
template<int DIM, int G, bool ATTN, bool DO_SELU, bool OUT_BF16, bool DOTS>
__global__ __launch_bounds__(256) void fused_gat(
    const int* __restrict__ off, const int* __restrict__ degs, const int* __restrict__ adj,
    const float* __restrict__ ps, const float* __restrict__ pd,
    const unsigned short* __restrict__ xin, void* __restrict__ out_,
    const float* __restrict__ un, const float* __restrict__ vn,
    float* __restrict__ psn, float* __restrict__ pdn_o, int N){
  constexpr int R = DIM / G;
  using V = typename VecT<R>::type;
  int t = blockIdx.x * 256 + threadIdx.x;
  int node = t / G;
  int gl = t % G;
  if (node >= N) return;
  int base = (threadIdx.x & 63) & ~(G - 1);
  int o = off[node], dg = degs[node];
  float acc[R] = {};

  auto ldv = [&](int nj) -> V {
    return *reinterpret_cast<const V*>(xin + (size_t)nj * DIM + gl * R);
  };
  auto vacc = [&](V u, float wj){
    if constexpr (R == 2){
      unpack_acc(acc, u, wj);
    } else if constexpr (R == 4){
      unpack_acc(acc, u.x, wj); unpack_acc(acc + 2, u.y, wj);
    } else {
      unpack_acc(acc, u.x, wj); unpack_acc(acc + 2, u.y, wj);
      unpack_acc(acc + 4, u.z, wj); unpack_acc(acc + 6, u.w, wj);
    }
  };
  auto batch8 = [&](int nid, float w, int j){
    int nn[8]; float ww[8]; V uu[8];
    #pragma unroll
    for (int q = 0; q < 8; q++){ nn[q] = __shfl(nid, base + j + q); ww[q] = __shfl(w, base + j + q); }
    #pragma unroll
    for (int q = 0; q < 8; q++) uu[q] = ldv(nn[q]);
    #pragma unroll
    for (int q = 0; q < 8; q++) vacc(uu[q], ww[q]);
  };
  auto batch4 = [&](int nid, float w, int j){
    int nn[4]; float ww[4]; V uu[4];
    #pragma unroll
    for (int q = 0; q < 4; q++){ nn[q] = __shfl(nid, base + j + q); ww[q] = __shfl(w, base + j + q); }
    #pragma unroll
    for (int q = 0; q < 4; q++) uu[q] = ldv(nn[q]);
    #pragma unroll
    for (int q = 0; q < 4; q++) vacc(uu[q], ww[q]);
  };

  if (ATTN){
    float pdn = pd[node];
    if (dg <= G){
      int nid = 0;
      float s = -1e30f;
      if (gl < dg){
        nid = adj[o + gl];
        s = ps[nid] + pdn;
        s = s > 0.f ? s : 0.2f * s;
      }
      float m = s;
      for (int msk = G >> 1; msk; msk >>= 1) m = fmaxf(m, __shfl_xor(m, msk));
      float e = (gl < dg) ? __expf(s - m) : 0.f;
      float den = e;
      for (int msk = G >> 1; msk; msk >>= 1) den += __shfl_xor(den, msk);
      float w = (dg > 0) ? e / den : 0.f;
      int j = 0;
      for (; j + 8 <= dg; j += 8) batch8(nid, w, j);
      for (; j + 4 <= dg; j += 4) batch4(nid, w, j);
      for (; j < dg; j++){
        int nj = __shfl(nid, base + j);
        float wj = __shfl(w, base + j);
        vacc(ldv(nj), wj);
      }
    } else {
      // generic 3-pass fallback (rare)
      float m = -1e30f;
      for (int k = gl; k < dg; k += G){
        float s = ps[adj[o + k]] + pdn;
        s = s > 0.f ? s : 0.2f * s;
        m = fmaxf(m, s);
      }
      for (int msk = G >> 1; msk; msk >>= 1) m = fmaxf(m, __shfl_xor(m, msk));
      float den = 0.f;
      for (int k = gl; k < dg; k += G){
        float s = ps[adj[o + k]] + pdn;
        s = s > 0.f ? s : 0.2f * s;
        den += __expf(s - m);
      }
      for (int msk = G >> 1; msk; msk >>= 1) den += __shfl_xor(den, msk);
      float inv = 1.f / den;
      for (int c0 = 0; c0 < dg; c0 += G){
        int cn = min(G, dg - c0);
        int nid = 0; float w = 0.f;
        if (gl < cn){
          nid = adj[o + c0 + gl];
          float s = ps[nid] + pdn;
          s = s > 0.f ? s : 0.2f * s;
          w = __expf(s - m) * inv;
        }
        int j = 0;
        for (; j + 8 <= cn; j += 8) batch8(nid, w, j);
        for (; j + 4 <= cn; j += 4) batch4(nid, w, j);
        for (; j < cn; j++){
          int nj = __shfl(nid, base + j);
          float wj = __shfl(w, base + j);
          vacc(ldv(nj), wj);
        }
      }
    }
  } else {
    for (int c0 = 0; c0 < dg; c0 += G){
      int cn = min(G, dg - c0);
      int nid = (gl < cn) ? adj[o + c0 + gl] : 0;
      float w1 = 1.f;
      int j = 0;
      for (; j + 8 <= cn; j += 8) batch8(nid, w1, j);
      for (; j + 4 <= cn; j += 4) batch4(nid, w1, j);
      for (; j < cn; j++){
        int nj = __shfl(nid, base + j);
        vacc(ldv(nj), 1.f);
      }
    }
    float inv = dg > 0 ? 1.f / (float)dg : 0.f;
    #pragma unroll
    for (int r = 0; r < R; r++) acc[r] *= inv;
  }
  if (DO_SELU){
    #pragma unroll
    for (int r = 0; r < R; r++) acc[r] = selu_f(acc[r]);
  }
  if (DOTS){
    float s1 = 0.f, s2 = 0.f;
    #pragma unroll
    for (int r = 0; r < R; r++){
      s1 += acc[r] * un[gl * R + r];
      s2 += acc[r] * vn[gl * R + r];
    }
    for (int msk = G >> 1; msk; msk >>= 1){ s1 += __shfl_xor(s1, msk); s2 += __shfl_xor(s2, msk); }
    if (gl == 0){ psn[node] = s1; pdn_o[node] = s2; }
  }
  if (OUT_BF16){
    unsigned short* out = (unsigned short*)out_;
    if constexpr (R == 2){
      *reinterpret_cast<unsigned*>(out + (size_t)node * DIM + gl * 2) = packbf(acc[0], acc[1]);
    } else if constexpr (R == 4){
      uint2 u; u.x = packbf(acc[0], acc[1]); u.y = packbf(acc[2], acc[3]);
      *reinterpret_cast<uint2*>(out + (size_t)node * DIM + gl * 4) = u;
    } else {
      uint4 u;
      u.x = packbf(acc[0], acc[1]); u.y = packbf(acc[2], acc[3]);
      u.z = packbf(acc[4], acc[5]); u.w = packbf(acc[6], acc[7]);
      *reinterpret_cast<uint4*>(out + (size_t)node * DIM + gl * 8) = u;
    }
  } else {
    float* out = (float*)out_;
    #pragma unroll
    for (int r = 0; r < R; r++) out[(size_t)node * DIM + gl * R + r] = acc[r];
  }
}

// ---------- fused smoothing step: G=8, uint2 (4 bf16) per lane ----------
template<bool OUT_B>
__global__ __launch_bounds__(256) void fused_smooth(
    const int* __restrict__ off, const int* __restrict__ degs, const int* __restrict__ adj,
    const float* __restrict__ pn, const float* __restrict__ qn,
    const float* __restrict__ scale,
    const unsigned short* __restrict__ xin, void* __restrict__ out_, int N){
  const int G = 8;
  int t = blockIdx.x * 256 + threadIdx.x;
  int node = t / G, gl = t % G;
  if (node >= N) return;
  int base = (threadIdx.x & 63) & ~(G - 1);
  int o = off[node], dg = degs[node];
  float pnv = pn[node] * (scale ? scale[0] : 1.f);
  float acc[4] = {};
  auto ldv = [&](int nj) -> uint2 {
    return *reinterpret_cast<const uint2*>(xin + (size_t)nj * 32 + gl * 4);
  };
  for (int c0 = 0; c0 < dg; c0 += G){
    int cn = min(G, dg - c0);
    int nid = 0; float qv = 0.f;
    if (gl < cn){ nid = adj[o + c0 + gl]; qv = qn[nid]; }
    if (cn == 8){
      int nn[8]; float ww[8]; uint2 uu[8];
      #pragma unroll
      for (int q = 0; q < 8; q++){ nn[q] = __shfl(nid, base + q); ww[q] = __shfl(qv, base + q); }
      #pragma unroll
      for (int q = 0; q < 8; q++) uu[q] = ldv(nn[q]);
      #pragma unroll
      for (int q = 0; q < 8; q++){ unpack_acc(acc, uu[q].x, ww[q]); unpack_acc(acc + 2, uu[q].y, ww[q]); }
    } else {
      for (int j = 0; j < cn; j++){
        int nj = __shfl(nid, base + j);
        float wj = __shfl(qv, base + j);
        uint2 u = ldv(nj);
        unpack_acc(acc, u.x, wj); unpack_acc(acc + 2, u.y, wj);
      }
    }
  }
  #pragma unroll
  for (int r = 0; r < 4; r++) acc[r] *= pnv;
  if (OUT_B){
    uint2 u; u.x = packbf(acc[0], acc[1]); u.y = packbf(acc[2], acc[3]);
    *reinterpret_cast<uint2*>((unsigned short*)out_ + (size_t)node * 32 + gl * 4) = u;
  } else {
    float4 v; v.x = acc[0]; v.y = acc[1]; v.z = acc[2]; v.w = acc[3];
    *reinterpret_cast<float4*>((float*)out_ + (size_t)node * 32 + gl * 4) = v;
  }
}

// ---------- small bf16 MFMA GEMM (direct loads; for xs2/h3) ----------
template<int D, int K, int CB, bool DO_SELU, bool OUT_BF16>
__global__ __launch_bounds__(256) void gemm_mfma(
    const unsigned short* __restrict__ A, const unsigned short* __restrict__ Bt,
    void* __restrict__ Cout, int M){
  constexpr int NF = CB / 16;
  int wave = threadIdx.x >> 6;
  int lane = threadIdx.x & 63;
  int row0 = blockIdx.x * 64 + wave * 16;
  int col0 = blockIdx.y * CB;
  int l15 = lane & 15;
  int arow = row0 + l15;
  int g8 = (lane >> 4) * 8;
  bool rowok = arow < M;
  f32x4 acc[NF] = {};
  for (int k0 = 0; k0 < D; k0 += 32){
    bf16x8 a = {};
    if (rowok) a = *reinterpret_cast<const bf16x8*>(A + (size_t)arow * D + k0 + g8);
    #pragma unroll
    for (int f = 0; f < NF; f++){
      bf16x8 b = *reinterpret_cast<const bf16x8*>(
          Bt + (size_t)(col0 + f * 16 + l15) * D + k0 + g8);
      acc[f] = __builtin_amdgcn_mfma_f32_16x16x32_bf16(b, a, acc[f], 0, 0, 0);
    }
  }
  if (!rowok) return;
  int cb = (lane >> 4) * 4;
  #pragma unroll
  for (int f = 0; f < NF; f++){
    float v0 = acc[f][0], v1 = acc[f][1], v2 = acc[f][2], v3 = acc[f][3];
    if (DO_SELU){ v0 = selu_f(v0); v1 = selu_f(v1); v2 = selu_f(v2); v3 = selu_f(v3); }
    size_t idx = (size_t)arow * K + col0 + f * 16 + cb;
    if (OUT_BF16){
      uint2 u;
      u.x = packbf(v0, v1);
      u.y = packbf(v2, v3);
      *reinterpret_cast<uint2*>((unsigned short*)Cout + idx) = u;
    } else {
      f32x4 v = { v0, v1, v2, v3 };
      __builtin_nontemporal_store(v, reinterpret_cast<f32x4*>((float*)Cout + idx));
    }
  }
}

// ---------- pipelined bf16 MFMA GEMM (global_load_lds staged; for xs1/h4) ----------
template<int D, int K, bool DO_SELU, bool OUT_BF16>
__global__ __launch_bounds__(256) void gemm_pipe(
    const unsigned short* __restrict__ A, const unsigned short* __restrict__ Bt,
    void* __restrict__ Cout, int M){
  constexpr int NK = D / 32;
  constexpr int NF = K / 32;
  constexpr int AG = 2 * NK;
  constexpr int BG = 2 * NF * NK;
  extern __shared__ unsigned short smem[];
  unsigned short* Bs  = smem;
  unsigned short* As0 = smem + (size_t)K * D;
  unsigned short* As1 = As0 + 32 * D;

  const int w = threadIdx.x >> 6;
  const int lane = threadIdx.x & 63;
  const int rw = w & 1, cw = w >> 1;
  const int l15 = lane & 15, lhi = lane >> 4;

  for (int g = w; g < BG; g += 4){
    int k = g % NK, ff = g / NK;
    gload_lds16(Bt + (size_t)(ff * 16 + l15) * D + k * 32 + lhi * 8,
                Bs + (size_t)g * 512);
  }

  const int ntiles = M / 32;
  const int stride = gridDim.x;
  int t = blockIdx.x;

  auto stageA = [&](unsigned short* dstp, int tile){
    int row0 = tile * 32;
    for (int g = w; g < AG; g += 4){
      int k = g % NK, rr = g / NK;
      gload_lds16(A + (size_t)(row0 + rr * 16 + l15) * D + k * 32 + lhi * 8,
                  dstp + (size_t)g * 512);
    }
  };

  if (t < ntiles) stageA(As0, t);
  __syncthreads();

  int cur = 0;
  for (; t < ntiles; t += stride){
    unsigned short* curA = cur ? As1 : As0;
    unsigned short* nxtA = cur ? As0 : As1;
    int tn = t + stride;
    if (tn < ntiles) stageA(nxtA, tn);

    f32x4 acc[NF] = {};
    const unsigned short* Aw = curA + (size_t)rw * NK * 512;
    #pragma unroll
    for (int k = 0; k < NK; k++){
      bf16x8 a = *reinterpret_cast<const bf16x8*>(Aw + ((size_t)k * 64 + lane) * 8);
      #pragma unroll
      for (int f = 0; f < NF; f++){
        bf16x8 b = *reinterpret_cast<const bf16x8*>(
            Bs + (((size_t)(cw * NF + f) * NK + k) * 64 + lane) * 8);
        acc[f] = __builtin_amdgcn_mfma_f32_16x16x32_bf16(b, a, acc[f], 0, 0, 0);
      }
    }
    int row = t * 32 + rw * 16 + l15;
    #pragma unroll
    for (int f = 0; f < NF; f++){
      float v0 = acc[f][0], v1 = acc[f][1], v2 = acc[f][2], v3 = acc[f][3];
      if (DO_SELU){ v0 = selu_f(v0); v1 = selu_f(v1); v2 = selu_f(v2); v3 = selu_f(v3); }
      size_t idx = (size_t)row * K + cw * (K / 2) + f * 16 + lhi * 4;
      if (OUT_BF16){
        uint2 u;
        u.x = packbf(v0, v1);
        u.y = packbf(v2, v3);
        *reinterpret_cast<uint2*>((unsigned short*)Cout + idx) = u;
      } else {
        f32x4 v = { v0, v1, v2, v3 };
        __builtin_nontemporal_store(v, reinterpret_cast<f32x4*>((float*)Cout + idx));
      }
    }
    __syncthreads();
    cur ^= 1;
  }
}

extern "C" void kernel_launch(void* const* d_in, const int* in_sizes, int n_in,
                              void* d_out, int out_size, void* d_ws, size_t ws_size,
                              hipStream_t stream){
  const float* X    = (const float*)d_in[0];
  const int*   eidx = (const int*)d_in[1];
  const float* W1s  = (const float*)d_in[2];
  const float* W1d  = (const float*)d_in[3];
  const float* a1s  = (const float*)d_in[4];
  const float* a1d  = (const float*)d_in[5];
  const float* W2s  = (const float*)d_in[6];
  const float* W2d  = (const float*)d_in[7];
  const float* a2s  = (const float*)d_in[8];
  const float* a2d  = (const float*)d_in[9];
  const float* a3s  = (const float*)d_in[10];
  const float* a3d  = (const float*)d_in[11];
  const float* alpha1 = (const float*)d_in[14];
  const float* alpha2 = (const float*)d_in[15];

  const int N = in_sizes[0] / 256;
  const int E = in_sizes[1] / 2;
  const int* src = eidx;
  const int* dst = eidx + E;
  const int NBK = (N + 511) >> 9;

  float* out_sm = (float*)d_out;                    // [N,32]
  float* out_h4 = (float*)d_out + (size_t)N * 32;   // [N,256]

  float* ws = (float*)d_ws;
  size_t o = 0;
  unsigned short* Xh  = (unsigned short*)(ws + o); o += (size_t)N * 128; // [N,256] bf16
  unsigned short* B1h = (unsigned short*)(ws + o); o += (size_t)N * 64;  // xs1 / h3
  unsigned short* H1h = (unsigned short*)(ws + o); o += (size_t)N * 64;  // h1 / agg4
  unsigned short* B3h = (unsigned short*)(ws + o); o += (size_t)N * 16;  // xs2
  unsigned short* H2h = (unsigned short*)(ws + o); o += (size_t)N * 16;  // h2 (bf16)
  unsigned short* AGG3h = (unsigned short*)(ws + o); o += (size_t)N * 16; // agg3
  unsigned short* T1h = (unsigned short*)(ws + o); o += (size_t)N * 16;  // smooth tmp
  unsigned short* T2h = (unsigned short*)(ws + o); o += (size_t)N * 16;  // smooth tmp
  float* ps_a = ws + o; o += N;
  float* pd_a = ws + o; o += N;
  float* ps_b = ws + o; o += N;
  float* pd_b = ws + o; o += N;
  int* deg_in  = (int*)(ws + o); o += N;
  int* deg_src = (int*)(ws + o); o += N;
  int* off_dst = (int*)(ws + o); o += N;
  int* off_src = (int*)(ws + o); o += N;
  int* adj_dst = (int*)(ws + o); o += E;
  int* adj_src = (int*)(ws + o); o += E;
  unsigned* stgD = (unsigned*)(ws + o); o += E;
  unsigned* stgS = (unsigned*)(ws + o); o += E;
  int* bcntD  = (int*)(ws + o); o += 256;
  int* bcntS  = (int*)(ws + o); o += 256;
  int* bbaseD = (int*)(ws + o); o += 260;
  int* bbaseS = (int*)(ws + o); o += 260;
  int* bcurD  = (int*)(ws + o); o += 260;
  int* bcurS  = (int*)(ws + o); o += 260;
  float* dis = ws + o; o += N;
  float* pna = ws + o; o += N;
  float* qn  = ws + o; o += N;
  unsigned short* W1sT_h = (unsigned short*)(ws + o); o += 128 * 256 / 2;
  unsigned short* W2sT_h = (unsigned short*)(ws + o); o += 32 * 128 / 2;
  unsigned short* W2s_h  = (unsigned short*)(ws + o); o += 128 * 32 / 2;
  unsigned short* W1s_h  = (unsigned short*)(ws + o); o += 256 * 128 / 2;
  float* u1 = ws + o; o += 256;
  float* v1 = ws + o; o += 256;
  float* u2 = ws + o; o += 128;
  float* v2 = ws + o; o += 128;
  float* u3 = ws + o; o += 32;
  float* v3 = ws + o; o += 32;
  float* sscale = ws + o; o += 1;

  const int TPB = 256;
  const int EBLK = (E + 4095) / 4096;
  const int RB = (N + 63) / 64;
  auto blocksFor = [](size_t n){ return (unsigned)((n + 255) / 256); };

  // ---- small precompute first (u1/v1 needed by cvt_dots) ----
  precompute_vecs<<<1, 256, 0, stream>>>(W1s, W1d, a1s, a1d, W2s, W2d, a2s, a2d,
                                         a3s, a3d, u1, v1, u2, v2, u3, v3,
                                         alpha1, alpha2, sscale);
  prep_weights<<<128, 256, 0, stream>>>(W1s, W2s, W1sT_h, W1s_h, W2sT_h, W2s_h);
  cvt_dots<<<blocksFor((size_t)N * 64), TPB, 0, stream>>>(X, Xh, u1, v1, ps_a, pd_a, N);

  // ---- bucketed CSR build (both CSRs) ----
  (void)hipMemsetAsync(bcntD, 0, 512 * 4, stream);
  bucket_hist<<<EBLK, TPB, 0, stream>>>(src, dst, bcntD, bcntS, E);
  bucket_scan<<<1, 256, 0, stream>>>(bcntD, bcntS, bbaseD, bbaseS, bcurD, bcurS, NBK);
  bin_stage<<<EBLK, TPB, 0, stream>>>(src, dst, bcurD, bcurS, stgD, stgS, E);
  place_csr<<<2 * NBK, TPB, 0, stream>>>(stgD, stgS, bbaseD, bbaseS,
                                         adj_dst, adj_src, deg_in, off_dst,
                                         deg_src, off_src, dis, pna, qn, N, NBK);

  // ---- GAT layer 1: X(256) -> h1(128); epilogue dots for layer 2 ----
  {
    size_t lds = ((size_t)128 * 256 + 2 * 32 * 256) * 2;  // 96 KiB
    gemm_pipe<256, 128, false, true><<<256, TPB, lds, stream>>>(Xh, W1sT_h, B1h, N); // xs1
  }
  fused_gat<128, 16, true, true, true, true><<<blocksFor((size_t)N * 16), TPB, 0, stream>>>(
      off_dst, deg_in, adj_dst, ps_a, pd_a, B1h, H1h, u2, v2, ps_b, pd_b, N); // h1

  // ---- GAT layer 2: h1(128) -> h2(32); epilogue dots for layer 3 ----
  { dim3 g(RB, 1); gemm_mfma<128, 32, 32, false, true><<<g, TPB, 0, stream>>>(H1h, W2sT_h, B3h, N); } // xs2
  fused_gat<32, 16, true, false, true, true><<<blocksFor((size_t)N * 16), TPB, 0, stream>>>(
      off_dst, deg_in, adj_dst, ps_b, pd_b, B3h, H2h, u3, v3, ps_a, pd_a, N); // h2 (bf16)

  // ---- GAT layer 3: h2(32) -> h3(128) ----
  fused_gat<32, 16, true, false, true, false><<<blocksFor((size_t)N * 16), TPB, 0, stream>>>(
      off_dst, deg_in, adj_dst, ps_a, pd_a, H2h, AGG3h, nullptr, nullptr, nullptr, nullptr, N);
  { dim3 g(RB, 2); gemm_mfma<32, 128, 64, true, true><<<g, TPB, 0, stream>>>(AGG3h, W2s_h, B1h, N); } // h3

  // ---- GAT layer 4 (uniform): aggregate h3 then GEMM with W1s^T ----
  fused_gat<128, 16, false, false, true, false><<<blocksFor((size_t)N * 16), TPB, 0, stream>>>(
      off_dst, deg_in, adj_dst, nullptr, nullptr, B1h, H1h, nullptr, nullptr, nullptr, nullptr, N);
  {
    size_t lds = ((size_t)256 * 128 + 2 * 32 * 128) * 2;  // 80 KiB
    gemm_pipe<128, 256, false, false><<<512, TPB, lds, stream>>>(H1h, W1s_h, out_h4, N); // h4
  }

  // ---- smoothing: sm = Norm^2 * (0.5(a1^2+4a2^2) * C^2 h2), bf16 tables ----
  fused_smooth<true><<<blocksFor((size_t)N * 8), TPB, 0, stream>>>(
      off_src, deg_src, adj_src, dis, dis, nullptr, H2h, T1h, N);
  fused_smooth<true><<<blocksFor((size_t)N * 8), TPB, 0, stream>>>(
      off_src, deg_src, adj_src, dis, dis, sscale, T1h, T2h, N);
  fused_smooth<true><<<blocksFor((size_t)N * 8), TPB, 0, stream>>>(
      off_src, deg_src, adj_src, pna, qn, nullptr, T2h, T1h, N);
  fused_smooth<false><<<blocksFor((size_t)N * 8), TPB, 0, stream>>>(
      off_src, deg_src, adj_src, pna, qn, nullptr, T1h, out_sm, N);
}